// Round 4
// baseline (587.398 us; speedup 1.0000x reference)
//
#include <hip/hip_runtime.h>
#include <hip/hip_bf16.h>
#include <cstddef>
#include <cstdint>

#define NB 8
#define LQ 8192
#define DMODEL 256
#define NHD 8
#define NLV 4
#define NPT 4
#define LEN_IN 19560          // 92*160 + 46*80 + 23*40 + 12*20
#define NQ (NB * LQ)          // 65536
#define MV (NB * LEN_IN)      // 156480
#define MVP 156544            // MV padded to multiple of 128 (1223*128)

using bf16x8 = __attribute__((ext_vector_type(8))) short;
using f32x4  = __attribute__((ext_vector_type(4))) float;

typedef const __attribute__((address_space(1))) void* gas_ptr;
typedef __attribute__((address_space(3))) void* las_ptr;

__device__ __forceinline__ void gl_lds16(const void* g, void* l) {
  __builtin_amdgcn_global_load_lds((gas_ptr)g, (las_ptr)l, 16, 0, 0);
}
__device__ __forceinline__ float bflo(unsigned u) {
  union { unsigned i; float f; } c; c.i = u << 16; return c.f;
}
__device__ __forceinline__ float bfhi(unsigned u) {
  union { unsigned i; float f; } c; c.i = u & 0xffff0000u; return c.f;
}
__device__ __forceinline__ bf16x8 pack8(float4 a, float4 b) {
  bf16x8 o;
  o[0] = (short)__bfloat16_as_ushort(__float2bfloat16(a.x));
  o[1] = (short)__bfloat16_as_ushort(__float2bfloat16(a.y));
  o[2] = (short)__bfloat16_as_ushort(__float2bfloat16(a.z));
  o[3] = (short)__bfloat16_as_ushort(__float2bfloat16(a.w));
  o[4] = (short)__bfloat16_as_ushort(__float2bfloat16(b.x));
  o[5] = (short)__bfloat16_as_ushort(__float2bfloat16(b.y));
  o[6] = (short)__bfloat16_as_ushort(__float2bfloat16(b.z));
  o[7] = (short)__bfloat16_as_ushort(__float2bfloat16(b.w));
  return o;
}

// ---------------------------------------------------------------------------
// W[256][N] fp32 -> Bt[N][256] bf16 (tiny; naive is fine)
// ---------------------------------------------------------------------------
__global__ __launch_bounds__(256) void transpose_bf16(
    const float* __restrict__ W, __hip_bfloat16* __restrict__ Bt, int N) {
  const int o = blockIdx.x * 256 + threadIdx.x;  // grid = N blocks
  const int n = o >> 8, k = o & 255;
  Bt[o] = __float2bfloat16(W[(size_t)k * N + n]);
}

// ---------------------------------------------------------------------------
// MFMA bf16 GEMM, 2-phase double-buffered: C[M,N] = A[M,256] @ B[256,N] + bias.
// A: fp32 row-major (A_F32=1, reg-staged issue-early/write-late) or bf16
// row-major (lds-dma). Bt: bf16 col-major [N][256].
// Block 256 thr = 4 waves, tile 128x128, BK=32, 8 K-tiles, ping-pong LDS.
// One barrier per K-step; stage(t+1) issued before compute(t) so the load
// latency hides under 16 MFMA + 8 ds_read (T3 minimum 2-phase pattern).
// OUT_MODE: 0 = fp32 row-major (bias)
//           2 = bf16 value_h scatter (bias)
//           3 = fused split: bn==0 -> fp32 logits N=128 (bias);
//               bn>=128   -> bf16 offb N=256 at col-128 (bias2)
// ---------------------------------------------------------------------------
template <int OUT_MODE, int A_F32>
__global__ __launch_bounds__(256) void gemm_mfma(
    const void* __restrict__ Av, const __hip_bfloat16* __restrict__ Bt,
    const float* __restrict__ bias, const float* __restrict__ bias2,
    void* __restrict__ Cout, void* __restrict__ Cout2, int N, int M_valid) {
  __shared__ __hip_bfloat16 As[2][128 * 32];  // ping-pong, 8192 B each
  __shared__ __hip_bfloat16 Bs[2][128 * 32];

  const int tid = threadIdx.x;
  const int wv = tid >> 6;
  const int lane = tid & 63;
  const int quad = lane >> 4;
  const int l16 = lane & 15;
  const int bm = blockIdx.y * 128;
  const int bn = blockIdx.x * 128;
  const int rw = (wv & 1) * 64;   // wave's row offset in tile
  const int cw = (wv >> 1) * 64;  // wave's col offset in tile

  // B staging (lds-dma): linear slot = tid*16 B (call 1), +4096 B (call 2)
  const __hip_bfloat16* gB = Bt + (size_t)(bn + (tid >> 2)) * 256 + (tid & 3) * 8;
  char* ldsB0 = (char*)&Bs[0][0] + wv * 1024;

  // A staging
  const __hip_bfloat16* gA16 = nullptr;
  const float* gA32 = nullptr;
  char* ldsA0 = (char*)&As[0][0] + wv * 1024;
  __hip_bfloat16* dA = nullptr;
  bool okA = true;
  if (A_F32) {
    const int r = tid >> 1, half = tid & 1;  // thread stages half a row (16 f)
    okA = (bm + r) < M_valid;
    gA32 = (const float*)Av + (size_t)(bm + r) * 256 + half * 16;
    dA = &As[0][0] + r * 32 + half * 16;
  } else {
    gA16 = (const __hip_bfloat16*)Av + (size_t)(bm + (tid >> 2)) * 256 +
           (tid & 3) * 8;
  }

  f32x4 acc[4][4] = {};

#define GL_B(t, buf)                                          \
  do {                                                        \
    gl_lds16(gB + (t) * 32, ldsB0 + (buf) * 8192);            \
    gl_lds16(gB + 64 * 256 + (t) * 32,                        \
             ldsB0 + (buf) * 8192 + 4096);                    \
  } while (0)
#define GL_A16(t, buf)                                        \
  do {                                                        \
    gl_lds16(gA16 + (t) * 32, ldsA0 + (buf) * 8192);          \
    gl_lds16(gA16 + 64 * 256 + (t) * 32,                      \
             ldsA0 + (buf) * 8192 + 4096);                    \
  } while (0)
#define LOADA32(t, f)                                         \
  do {                                                        \
    if (okA) {                                                \
      f[0] = *(const float4*)(gA32 + (t) * 32);               \
      f[1] = *(const float4*)(gA32 + (t) * 32 + 4);           \
      f[2] = *(const float4*)(gA32 + (t) * 32 + 8);           \
      f[3] = *(const float4*)(gA32 + (t) * 32 + 12);          \
    } else {                                                  \
      f[0] = f[1] = f[2] = f[3] = make_float4(0, 0, 0, 0);    \
    }                                                         \
  } while (0)
#define PACKA(buf, f)                                         \
  do {                                                        \
    *(bf16x8*)(dA + (buf) * 4096) = pack8(f[0], f[1]);        \
    *(bf16x8*)(dA + (buf) * 4096 + 8) = pack8(f[2], f[3]);    \
  } while (0)
#define COMPUTE(buf)                                                        \
  do {                                                                      \
    bf16x8 af[4], bfr[4];                                                   \
    _Pragma("unroll") for (int t = 0; t < 4; ++t) {                         \
      af[t] = *(const bf16x8*)(&As[0][0] + (buf) * 4096 +                   \
                               (rw + t * 16 + l16) * 32 + quad * 8);        \
      bfr[t] = *(const bf16x8*)(&Bs[0][0] + (buf) * 4096 +                  \
                                (cw + t * 16 + l16) * 32 + quad * 8);       \
    }                                                                       \
    _Pragma("unroll") for (int i = 0; i < 4; ++i)                           \
        _Pragma("unroll") for (int j = 0; j < 4; ++j) acc[i][j] =           \
        __builtin_amdgcn_mfma_f32_16x16x32_bf16(af[i], bfr[j], acc[i][j],   \
                                                0, 0, 0);                   \
  } while (0)

  // prologue: stage tile 0 -> buf0
  {
    float4 f[4];
    if (A_F32) LOADA32(0, f);
    GL_B(0, 0);
    if (!A_F32) GL_A16(0, 0);
    if (A_F32) PACKA(0, f);
  }
  __syncthreads();  // tile 0 resident

#pragma unroll 1
  for (int tt = 0; tt < 4; ++tt) {
    // seg A: stage tile 2tt+1 -> buf1, compute tile 2tt (buf0)
    {
      float4 fb[4];
      if (A_F32) LOADA32(2 * tt + 1, fb);
      GL_B(2 * tt + 1, 1);
      if (!A_F32) GL_A16(2 * tt + 1, 1);
      COMPUTE(0);
      if (A_F32) PACKA(1, fb);  // write-late: loads had MFMA phase to land
    }
    __syncthreads();  // tile 2tt+1 resident; buf0 free
    // seg B: stage tile 2tt+2 -> buf0, compute tile 2tt+1 (buf1)
    if (tt < 3) {
      float4 fc[4];
      if (A_F32) LOADA32(2 * tt + 2, fc);
      GL_B(2 * tt + 2, 0);
      if (!A_F32) GL_A16(2 * tt + 2, 0);
      COMPUTE(1);
      if (A_F32) PACKA(0, fc);
    } else {
      COMPUTE(1);
    }
    __syncthreads();
  }

#undef GL_B
#undef GL_A16
#undef LOADA32
#undef PACKA
#undef COMPUTE

  // Epilogue. C/D layout: col = lane&15, row = quad*4 + reg.
#pragma unroll
  for (int j = 0; j < 4; ++j) {
    const int col = bn + cw + j * 16 + l16;
    float bb;
    if (OUT_MODE == 3)
      bb = (bn == 0) ? bias[col] : bias2[col - 128];
    else
      bb = bias[col];
#pragma unroll
    for (int i = 0; i < 4; ++i) {
#pragma unroll
      for (int r = 0; r < 4; ++r) {
        const int row = bm + rw + i * 16 + quad * 4 + r;
        const float v = acc[i][j][r] + bb;
        if (OUT_MODE == 0) {
          ((float*)Cout)[(size_t)row * N + col] = v;
        } else if (OUT_MODE == 2) {
          if (row < M_valid) {
            const int b = row / LEN_IN;
            const int pix = row - b * LEN_IN;
            const int h = col >> 5, ch = col & 31;
            ((__hip_bfloat16*)Cout)[(((size_t)(b * 8 + h) * LEN_IN + pix) << 5) +
                                    ch] = __float2bfloat16(v);
          }
        } else {  // OUT_MODE == 3
          if (bn == 0) {
            ((float*)Cout)[(size_t)row * 128 + col] = v;
          } else {
            ((__hip_bfloat16*)Cout2)[(size_t)row * 256 + (col - 128)] =
                __float2bfloat16(v);
          }
        }
      }
    }
  }
}

// ---------------------------------------------------------------------------
// Sampler v5: 2 queries per 256-thread block.
// Phase 1 unchanged (softmax + descriptor build into LDS).
// Phase 2: 4-point software-pipelined gather — 4 uint4 loads in flight,
// next group's descriptors + loads issued before current group's FMAs.
// ---------------------------------------------------------------------------
__global__ __launch_bounds__(256) void msda_sample5(
    const float* __restrict__ refp,            // (NQ, 8)
    const float* __restrict__ logits,          // (NQ, 128) fp32 raw
    const __hip_bfloat16* __restrict__ offb,   // (NQ, 256) bf16
    const __hip_bfloat16* __restrict__ vh,     // (NB*8, LEN_IN, 32)
    __hip_bfloat16* __restrict__ mid) {        // (NQ, 256) bf16
  const int q0 = blockIdx.x * 2;
  const int tid = threadIdx.x;

  __shared__ int2 s_d[2][8][17][4];

  {
    const int sq = tid >> 7;
    const int t = tid & 127;  // (h*NLV + l)*NPT + p  == h*16 + l*4 + p
    const int qg = q0 + sq;
    const int l = (t >> 2) & 3;
    constexpr int Hs[4] = {92, 46, 23, 12};
    constexpr int Ws_[4] = {160, 80, 40, 20};
    constexpr int St[4] = {0, 14720, 18400, 19320};
    const int Hl = Hs[l], Wl = Ws_[l];

    const float lg = logits[(size_t)qg * 128 + t];
    float mx = lg;
#pragma unroll
    for (int d = 1; d < 16; d <<= 1) mx = fmaxf(mx, __shfl_xor(mx, d));
    const float e = expf(lg - mx);
    float sm = e;
#pragma unroll
    for (int d = 1; d < 16; d <<= 1) sm += __shfl_xor(sm, d);
    const float w = e / sm;

    const float rx = refp[(size_t)qg * 8 + 2 * l];
    const float ry = refp[(size_t)qg * 8 + 2 * l + 1];
    const unsigned uo = *(const unsigned*)(offb + (size_t)qg * 256 + 2 * t);
    const float ox = bflo(uo), oy = bfhi(uo);

    const float x = rx * (float)Wl + ox - 0.5f;
    const float y = ry * (float)Hl + oy - 0.5f;
    const float xf = floorf(x), yf = floorf(y);
    const float wx = x - xf, wy = y - yf;
    const int x0 = (int)xf, y0 = (int)yf;
    const int x1 = x0 + 1, y1 = y0 + 1;
    const bool vx0 = (x0 >= 0) & (x0 < Wl), vx1 = (x1 >= 0) & (x1 < Wl);
    const bool vy0 = (y0 >= 0) & (y0 < Hl), vy1 = (y1 >= 0) & (y1 < Hl);
    const int cx0 = min(max(x0, 0), Wl - 1), cx1 = min(max(x1, 0), Wl - 1);
    const int cy0 = min(max(y0, 0), Hl - 1), cy1 = min(max(y1, 0), Hl - 1);

    const int o00 = (St[l] + cy0 * Wl + cx0) * 64;  // 64 B per pixel
    const int o01 = (St[l] + cy1 * Wl + cx0) * 64;
    const int dx = (cx1 - cx0) * 64;                // 0 or 64

    int2* dd = s_d[sq][t >> 4][t & 15];
    dd[0] = make_int2(o00,      __float_as_int((vx0 & vy0) ? w * (1.f - wx) * (1.f - wy) : 0.f));
    dd[1] = make_int2(o00 + dx, __float_as_int((vx1 & vy0) ? w * wx * (1.f - wy) : 0.f));
    dd[2] = make_int2(o01,      __float_as_int((vx0 & vy1) ? w * (1.f - wx) * wy : 0.f));
    dd[3] = make_int2(o01 + dx, __float_as_int((vx1 & vy1) ? w * wx * wy : 0.f));
  }
  __syncthreads();

  const int tap = tid & 3;
  const int cg = (tid >> 2) & 3;   // 4 channel-groups x 8 ch = 32 ch
  const int h = (tid >> 4) & 7;
  const int sq = tid >> 7;
  const int qg = q0 + sq;
  const int bq = q0 >> 13;         // batch; same for both sub-queries

  const char* vbase = (const char*)vh + (size_t)bq * (8ULL * LEN_IN * 64);
  const int voff0 = h * (LEN_IN * 64) + cg * 16;
  const int2* sd = &s_d[sq][h][0][tap];

  float a[8] = {};
  int2 d[4];
  uint4 u[4];
#pragma unroll
  for (int j = 0; j < 4; ++j) d[j] = sd[j * 4];
#pragma unroll
  for (int j = 0; j < 4; ++j)
    u[j] = *(const uint4*)(vbase + (unsigned)(voff0 + d[j].x));

#pragma unroll
  for (int g = 0; g < 4; ++g) {
    int2 dn[4];
    uint4 un[4];
    if (g < 3) {
#pragma unroll
      for (int j = 0; j < 4; ++j) dn[j] = sd[(g * 4 + 4 + j) * 4];
#pragma unroll
      for (int j = 0; j < 4; ++j)
        un[j] = *(const uint4*)(vbase + (unsigned)(voff0 + dn[j].x));
    }
#pragma unroll
    for (int j = 0; j < 4; ++j) {
      const float w = __int_as_float(d[j].y);
      const uint4 uu = u[j];
      a[0] += w * bflo(uu.x); a[1] += w * bfhi(uu.x);
      a[2] += w * bflo(uu.y); a[3] += w * bfhi(uu.y);
      a[4] += w * bflo(uu.z); a[5] += w * bfhi(uu.z);
      a[6] += w * bflo(uu.w); a[7] += w * bfhi(uu.w);
    }
    if (g < 3) {
#pragma unroll
      for (int j = 0; j < 4; ++j) {
        d[j] = dn[j];
        u[j] = un[j];
      }
    }
  }

#pragma unroll
  for (int i = 0; i < 8; ++i) a[i] += __shfl_xor(a[i], 1);
#pragma unroll
  for (int i = 0; i < 8; ++i) a[i] += __shfl_xor(a[i], 2);

  if (tap == 0) {
    unsigned short* mp =
        (unsigned short*)mid + (size_t)qg * 256 + h * 32 + cg * 8;
    int4 o;
    o.x = (int)((unsigned)__bfloat16_as_ushort(__float2bfloat16(a[0])) |
                ((unsigned)__bfloat16_as_ushort(__float2bfloat16(a[1])) << 16));
    o.y = (int)((unsigned)__bfloat16_as_ushort(__float2bfloat16(a[2])) |
                ((unsigned)__bfloat16_as_ushort(__float2bfloat16(a[3])) << 16));
    o.z = (int)((unsigned)__bfloat16_as_ushort(__float2bfloat16(a[4])) |
                ((unsigned)__bfloat16_as_ushort(__float2bfloat16(a[5])) << 16));
    o.w = (int)((unsigned)__bfloat16_as_ushort(__float2bfloat16(a[6])) |
                ((unsigned)__bfloat16_as_ushort(__float2bfloat16(a[7])) << 16));
    *(int4*)mp = o;
  }
}

// ---------------------------------------------------------------------------
// Launch
// ---------------------------------------------------------------------------
extern "C" void kernel_launch(void* const* d_in, const int* in_sizes, int n_in,
                              void* d_out, int out_size, void* d_ws,
                              size_t ws_size, hipStream_t stream) {
  const float* query = (const float*)d_in[0];
  const float* refp = (const float*)d_in[1];
  const float* inflat = (const float*)d_in[2];
  const float* W_off = (const float*)d_in[5];
  const float* b_off = (const float*)d_in[6];
  const float* W_attn = (const float*)d_in[7];
  const float* b_attn = (const float*)d_in[8];
  const float* W_val = (const float*)d_in[9];
  const float* b_val = (const float*)d_in[10];
  const float* W_out = (const float*)d_in[11];
  const float* b_out = (const float*)d_in[12];
  float* out = (float*)d_out;

  // Workspace layout (bytes):
  char* ws = (char*)d_ws;
  __hip_bfloat16* vh = (__hip_bfloat16*)(ws);                    // [64][19560][32]
  float* logits = (float*)(ws + 80117760ULL);                    // [65536][128] f32
  __hip_bfloat16* offb = (__hip_bfloat16*)(ws + 113672192ULL);   // [65536][256]
  __hip_bfloat16* mid = (__hip_bfloat16*)(ws + 147226624ULL);    // [65536][256]
  __hip_bfloat16* Btv = (__hip_bfloat16*)(ws + 180781056ULL);    // [256][256]
  __hip_bfloat16* Btc = (__hip_bfloat16*)(ws + 180912128ULL);    // [384][256] attn||off
  __hip_bfloat16* Btw = (__hip_bfloat16*)(ws + 181108736ULL);    // [256][256]
  // total 181,239,808 B

  // weight transposes (tiny)
  transpose_bf16<<<256, 256, 0, stream>>>(W_val, Btv, 256);
  transpose_bf16<<<128, 256, 0, stream>>>(W_attn, Btc, 128);
  transpose_bf16<<<256, 256, 0, stream>>>(W_off, Btc + 128 * 256, 256);
  transpose_bf16<<<256, 256, 0, stream>>>(W_out, Btw, 256);

  // 1. value = inflat @ W_val + b_val -> head-major bf16 value_h  (A fp32)
  gemm_mfma<2, 1><<<dim3(2, MVP / 128), 256, 0, stream>>>(
      inflat, Btv, b_val, nullptr, vh, nullptr, 256, MV);
  // 2+3 fused: [logits | offsets] = query @ [W_attn | W_off]  (A fp32)
  gemm_mfma<3, 1><<<dim3(3, NQ / 128), 256, 0, stream>>>(
      query, Btc, b_attn, b_off, logits, offb, 384, NQ);
  // 4. sampling (softmax fused, 2 queries/block) -> mid bf16
  msda_sample5<<<NQ / 2, 256, 0, stream>>>(refp, logits, offb, vh, mid);
  // 5. out = mid @ W_out + b_out -> fp32 d_out  (A bf16, lds-dma)
  gemm_mfma<0, 0><<<dim3(2, NQ / 128), 256, 0, stream>>>(
      mid, Btw, b_out, nullptr, out, nullptr, 256, NQ);
}

// Round 5
// 530.084 us; speedup vs baseline: 1.1081x; 1.1081x over previous
//
#include <hip/hip_runtime.h>
#include <hip/hip_bf16.h>
#include <cstddef>
#include <cstdint>

#define NB 8
#define LQ 8192
#define DMODEL 256
#define NHD 8
#define NLV 4
#define NPT 4
#define LEN_IN 19560          // 92*160 + 46*80 + 23*40 + 12*20
#define NQ (NB * LQ)          // 65536
#define MV (NB * LEN_IN)      // 156480
#define MVP 156544            // MV padded to multiple of 128 (1223*128)

using bf16x8 = __attribute__((ext_vector_type(8))) short;
using f32x4  = __attribute__((ext_vector_type(4))) float;

typedef const __attribute__((address_space(1))) void* gas_ptr;
typedef __attribute__((address_space(3))) void* las_ptr;

__device__ __forceinline__ void gl_lds16(const void* g, void* l) {
  __builtin_amdgcn_global_load_lds((gas_ptr)g, (las_ptr)l, 16, 0, 0);
}
__device__ __forceinline__ float bflo(unsigned u) {
  union { unsigned i; float f; } c; c.i = u << 16; return c.f;
}
__device__ __forceinline__ float bfhi(unsigned u) {
  union { unsigned i; float f; } c; c.i = u & 0xffff0000u; return c.f;
}
__device__ __forceinline__ bf16x8 pack8(float4 a, float4 b) {
  bf16x8 o;
  o[0] = (short)__bfloat16_as_ushort(__float2bfloat16(a.x));
  o[1] = (short)__bfloat16_as_ushort(__float2bfloat16(a.y));
  o[2] = (short)__bfloat16_as_ushort(__float2bfloat16(a.z));
  o[3] = (short)__bfloat16_as_ushort(__float2bfloat16(a.w));
  o[4] = (short)__bfloat16_as_ushort(__float2bfloat16(b.x));
  o[5] = (short)__bfloat16_as_ushort(__float2bfloat16(b.y));
  o[6] = (short)__bfloat16_as_ushort(__float2bfloat16(b.z));
  o[7] = (short)__bfloat16_as_ushort(__float2bfloat16(b.w));
  return o;
}

// ---------------------------------------------------------------------------
// W[256][N] fp32 -> Bt[N][256] bf16 (tiny; naive is fine)
// ---------------------------------------------------------------------------
__global__ __launch_bounds__(256) void transpose_bf16(
    const float* __restrict__ W, __hip_bfloat16* __restrict__ Bt, int N) {
  const int o = blockIdx.x * 256 + threadIdx.x;  // grid = N blocks
  const int n = o >> 8, k = o & 255;
  Bt[o] = __float2bfloat16(W[(size_t)k * N + n]);
}

// ---------------------------------------------------------------------------
// MFMA bf16 GEMM, full-N per block: C[M, NT] = A[M,256] @ B[256,NT] + bias.
// 512 threads = 8 waves, wave grid 2(M) x 4(N): wave = 64 x (NT/4).
// A read exactly ONCE (no N-split duplicate reads). Single-buffered LDS,
// 2 barriers per K-step (R2 structure; explicit dbuf regressed in R4).
// A: fp32 row-major (A_F32=1, reg-load + cvt + ds_write, issue-early) or
// bf16 row-major (lds-dma). Bt: bf16 col-major [NT][256].
// OUT_MODE: 0 = fp32 row-major [M][NT]
//           2 = bf16 value_h scatter
//           3 = fused split: col<128 -> fp32 logits [M][128];
//               col>=128   -> bf16 offb [M][256] (bias2)
// ---------------------------------------------------------------------------
template <int OUT_MODE, int A_F32, int NT>
__global__ __launch_bounds__(512) void gemm_mfma(
    const void* __restrict__ Av, const __hip_bfloat16* __restrict__ Bt,
    const float* __restrict__ bias, const float* __restrict__ bias2,
    void* __restrict__ Cout, void* __restrict__ Cout2, int M_valid) {
  constexpr int NJ = NT / 64;  // j-fragments per wave (4 or 6)
  __shared__ __hip_bfloat16 As[128 * 32];  // [m][k], 8 KB
  __shared__ __hip_bfloat16 Bs[NT * 32];   // [n][k], 16/24 KB

  const int tid = threadIdx.x;
  const int wv = tid >> 6;
  const int lane = tid & 63;
  const int quad = lane >> 4;
  const int l16 = lane & 15;
  const int bm = blockIdx.x * 128;
  const int rw = (wv & 1) * 64;            // wave's row offset
  const int cwave = (wv >> 1) * (NT / 4);  // wave's col offset

  // B staging (lds-dma): call c covers rows c*128..c*128+127 of Bt.
  // 512 thr x 16 B = 8 KB per call; slot tid -> n = tid>>2, k8 = (tid&3)*8.
  const __hip_bfloat16* gB = Bt + (size_t)(tid >> 2) * 256 + (tid & 3) * 8;

  // A staging
  const __hip_bfloat16* gA16 = nullptr;
  const float* gA32 = nullptr;
  __hip_bfloat16* dA = nullptr;
  bool okA = true;
  if (A_F32) {
    const int r = tid >> 2, seg = tid & 3;  // 8 elems (16 B bf16) per thread
    okA = (bm + r) < M_valid;
    gA32 = (const float*)Av + (size_t)(bm + r) * 256 + seg * 8;
    dA = As + r * 32 + seg * 8;
  } else {
    gA16 = (const __hip_bfloat16*)Av + (size_t)(bm + (tid >> 2)) * 256 +
           (tid & 3) * 8;
  }

  f32x4 acc[4][NJ] = {};

#pragma unroll 1
  for (int k0 = 0; k0 < 256; k0 += 32) {
    float4 f0, f1;
    if (A_F32) {
      if (okA) {
        f0 = *(const float4*)(gA32 + k0);
        f1 = *(const float4*)(gA32 + k0 + 4);
      } else {
        f0 = f1 = make_float4(0.f, 0.f, 0.f, 0.f);
      }
    }
    __syncthreads();  // all waves done reading LDS before overwrite
#pragma unroll
    for (int c = 0; c < NT / 128; ++c)
      gl_lds16(gB + (size_t)c * 128 * 256 + k0,
               (char*)Bs + c * 8192 + wv * 1024);
    if (A_F32) {
      *(bf16x8*)dA = pack8(f0, f1);
    } else {
      gl_lds16(gA16 + k0, (char*)As + wv * 1024);
    }
    __syncthreads();  // tiles resident (vmcnt+lgkm drain at barrier)

    bf16x8 af[4], bfr[NJ];
#pragma unroll
    for (int t = 0; t < 4; ++t)
      af[t] = *(const bf16x8*)(As + (rw + t * 16 + l16) * 32 + quad * 8);
#pragma unroll
    for (int j = 0; j < NJ; ++j)
      bfr[j] = *(const bf16x8*)(Bs + (cwave + j * 16 + l16) * 32 + quad * 8);
#pragma unroll
    for (int i = 0; i < 4; ++i)
#pragma unroll
      for (int j = 0; j < NJ; ++j)
        acc[i][j] = __builtin_amdgcn_mfma_f32_16x16x32_bf16(af[i], bfr[j],
                                                            acc[i][j], 0, 0, 0);
  }

  // Epilogue. C/D layout: col = lane&15, row = quad*4 + reg.
#pragma unroll
  for (int j = 0; j < NJ; ++j) {
    const int col = cwave + j * 16 + l16;
    float bb;
    if (OUT_MODE == 3)
      bb = (col < 128) ? bias[col] : bias2[col - 128];
    else
      bb = bias[col];
#pragma unroll
    for (int i = 0; i < 4; ++i) {
#pragma unroll
      for (int r = 0; r < 4; ++r) {
        const int row = bm + rw + i * 16 + quad * 4 + r;
        const float v = acc[i][j][r] + bb;
        if (OUT_MODE == 0) {
          ((float*)Cout)[(size_t)row * NT + col] = v;
        } else if (OUT_MODE == 2) {
          if (row < M_valid) {
            const int b = row / LEN_IN;
            const int pix = row - b * LEN_IN;
            const int h = col >> 5, ch = col & 31;
            ((__hip_bfloat16*)Cout)[(((size_t)(b * 8 + h) * LEN_IN + pix) << 5) +
                                    ch] = __float2bfloat16(v);
          }
        } else {  // OUT_MODE == 3
          if (col < 128) {
            ((float*)Cout)[(size_t)row * 128 + col] = v;
          } else {
            ((__hip_bfloat16*)Cout2)[(size_t)row * 256 + (col - 128)] =
                __float2bfloat16(v);
          }
        }
      }
    }
  }
}

// ---------------------------------------------------------------------------
// Sampler v6: 2 queries per 256-thread block.
// Phase 1 unchanged (softmax + descriptor build into LDS).
// Phase 2: ALL 16 point-descriptors read, then ALL 16 uint4 gathers issued
// before any FMA (forces ~16 loads in flight per wave; launch_bounds(256,4)
// caps VGPR at 128 so occupancy stays 16 waves/CU).
// ---------------------------------------------------------------------------
__global__ __launch_bounds__(256, 4) void msda_sample6(
    const float* __restrict__ refp,            // (NQ, 8)
    const float* __restrict__ logits,          // (NQ, 128) fp32 raw
    const __hip_bfloat16* __restrict__ offb,   // (NQ, 256) bf16
    const __hip_bfloat16* __restrict__ vh,     // (NB*8, LEN_IN, 32)
    __hip_bfloat16* __restrict__ mid) {        // (NQ, 256) bf16
  const int q0 = blockIdx.x * 2;
  const int tid = threadIdx.x;

  __shared__ int2 s_d[2][8][17][4];

  {
    const int sq = tid >> 7;
    const int t = tid & 127;  // (h*NLV + l)*NPT + p  == h*16 + l*4 + p
    const int qg = q0 + sq;
    const int l = (t >> 2) & 3;
    constexpr int Hs[4] = {92, 46, 23, 12};
    constexpr int Ws_[4] = {160, 80, 40, 20};
    constexpr int St[4] = {0, 14720, 18400, 19320};
    const int Hl = Hs[l], Wl = Ws_[l];

    const float lg = logits[(size_t)qg * 128 + t];
    float mx = lg;
#pragma unroll
    for (int d = 1; d < 16; d <<= 1) mx = fmaxf(mx, __shfl_xor(mx, d));
    const float e = expf(lg - mx);
    float sm = e;
#pragma unroll
    for (int d = 1; d < 16; d <<= 1) sm += __shfl_xor(sm, d);
    const float w = e / sm;

    const float rx = refp[(size_t)qg * 8 + 2 * l];
    const float ry = refp[(size_t)qg * 8 + 2 * l + 1];
    const unsigned uo = *(const unsigned*)(offb + (size_t)qg * 256 + 2 * t);
    const float ox = bflo(uo), oy = bfhi(uo);

    const float x = rx * (float)Wl + ox - 0.5f;
    const float y = ry * (float)Hl + oy - 0.5f;
    const float xf = floorf(x), yf = floorf(y);
    const float wx = x - xf, wy = y - yf;
    const int x0 = (int)xf, y0 = (int)yf;
    const int x1 = x0 + 1, y1 = y0 + 1;
    const bool vx0 = (x0 >= 0) & (x0 < Wl), vx1 = (x1 >= 0) & (x1 < Wl);
    const bool vy0 = (y0 >= 0) & (y0 < Hl), vy1 = (y1 >= 0) & (y1 < Hl);
    const int cx0 = min(max(x0, 0), Wl - 1), cx1 = min(max(x1, 0), Wl - 1);
    const int cy0 = min(max(y0, 0), Hl - 1), cy1 = min(max(y1, 0), Hl - 1);

    const int o00 = (St[l] + cy0 * Wl + cx0) * 64;  // 64 B per pixel
    const int o01 = (St[l] + cy1 * Wl + cx0) * 64;
    const int dx = (cx1 - cx0) * 64;                // 0 or 64

    int2* dd = s_d[sq][t >> 4][t & 15];
    dd[0] = make_int2(o00,      __float_as_int((vx0 & vy0) ? w * (1.f - wx) * (1.f - wy) : 0.f));
    dd[1] = make_int2(o00 + dx, __float_as_int((vx1 & vy0) ? w * wx * (1.f - wy) : 0.f));
    dd[2] = make_int2(o01,      __float_as_int((vx0 & vy1) ? w * (1.f - wx) * wy : 0.f));
    dd[3] = make_int2(o01 + dx, __float_as_int((vx1 & vy1) ? w * wx * wy : 0.f));
  }
  __syncthreads();

  const int tap = tid & 3;
  const int cg = (tid >> 2) & 3;   // 4 channel-groups x 8 ch = 32 ch
  const int h = (tid >> 4) & 7;
  const int sq = tid >> 7;
  const int qg = q0 + sq;
  const int bq = q0 >> 13;         // batch; same for both sub-queries

  const char* vbase = (const char*)vh + (size_t)bq * (8ULL * LEN_IN * 64);
  const int voff0 = h * (LEN_IN * 64) + cg * 16;
  const int2* sd = &s_d[sq][h][0][tap];

  // issue ALL 16 gathers before any use
  float w[16];
  uint4 u[16];
#pragma unroll
  for (int j = 0; j < 16; ++j) {
    const int2 dw = sd[j * 4];  // ds_read_b64, imm offset j*32
    w[j] = __int_as_float(dw.y);
    u[j] = *(const uint4*)(vbase + (unsigned)(voff0 + dw.x));
  }

  float a[8] = {};
#pragma unroll
  for (int j = 0; j < 16; ++j) {
    a[0] += w[j] * bflo(u[j].x); a[1] += w[j] * bfhi(u[j].x);
    a[2] += w[j] * bflo(u[j].y); a[3] += w[j] * bfhi(u[j].y);
    a[4] += w[j] * bflo(u[j].z); a[5] += w[j] * bfhi(u[j].z);
    a[6] += w[j] * bflo(u[j].w); a[7] += w[j] * bfhi(u[j].w);
  }

  // reduce over the 4 tap lanes (quad-local -> DPP adds)
#pragma unroll
  for (int i = 0; i < 8; ++i) a[i] += __shfl_xor(a[i], 1);
#pragma unroll
  for (int i = 0; i < 8; ++i) a[i] += __shfl_xor(a[i], 2);

  if (tap == 0) {
    unsigned short* mp =
        (unsigned short*)mid + (size_t)qg * 256 + h * 32 + cg * 8;
    int4 o;
    o.x = (int)((unsigned)__bfloat16_as_ushort(__float2bfloat16(a[0])) |
                ((unsigned)__bfloat16_as_ushort(__float2bfloat16(a[1])) << 16));
    o.y = (int)((unsigned)__bfloat16_as_ushort(__float2bfloat16(a[2])) |
                ((unsigned)__bfloat16_as_ushort(__float2bfloat16(a[3])) << 16));
    o.z = (int)((unsigned)__bfloat16_as_ushort(__float2bfloat16(a[4])) |
                ((unsigned)__bfloat16_as_ushort(__float2bfloat16(a[5])) << 16));
    o.w = (int)((unsigned)__bfloat16_as_ushort(__float2bfloat16(a[6])) |
                ((unsigned)__bfloat16_as_ushort(__float2bfloat16(a[7])) << 16));
    *(int4*)mp = o;
  }
}

// ---------------------------------------------------------------------------
// Launch
// ---------------------------------------------------------------------------
extern "C" void kernel_launch(void* const* d_in, const int* in_sizes, int n_in,
                              void* d_out, int out_size, void* d_ws,
                              size_t ws_size, hipStream_t stream) {
  const float* query = (const float*)d_in[0];
  const float* refp = (const float*)d_in[1];
  const float* inflat = (const float*)d_in[2];
  const float* W_off = (const float*)d_in[5];
  const float* b_off = (const float*)d_in[6];
  const float* W_attn = (const float*)d_in[7];
  const float* b_attn = (const float*)d_in[8];
  const float* W_val = (const float*)d_in[9];
  const float* b_val = (const float*)d_in[10];
  const float* W_out = (const float*)d_in[11];
  const float* b_out = (const float*)d_in[12];
  float* out = (float*)d_out;

  // Workspace layout (bytes):
  char* ws = (char*)d_ws;
  __hip_bfloat16* vh = (__hip_bfloat16*)(ws);                    // [64][19560][32]
  float* logits = (float*)(ws + 80117760ULL);                    // [65536][128] f32
  __hip_bfloat16* offb = (__hip_bfloat16*)(ws + 113672192ULL);   // [65536][256]
  __hip_bfloat16* mid = (__hip_bfloat16*)(ws + 147226624ULL);    // [65536][256]
  __hip_bfloat16* Btv = (__hip_bfloat16*)(ws + 180781056ULL);    // [256][256]
  __hip_bfloat16* Btc = (__hip_bfloat16*)(ws + 180912128ULL);    // [384][256] attn||off
  __hip_bfloat16* Btw = (__hip_bfloat16*)(ws + 181108736ULL);    // [256][256]
  // total 181,239,808 B

  // weight transposes (tiny)
  transpose_bf16<<<256, 256, 0, stream>>>(W_val, Btv, 256);
  transpose_bf16<<<128, 256, 0, stream>>>(W_attn, Btc, 128);
  transpose_bf16<<<256, 256, 0, stream>>>(W_off, Btc + 128 * 256, 256);
  transpose_bf16<<<256, 256, 0, stream>>>(W_out, Btw, 256);

  // 1. value = inflat @ W_val + b_val -> head-major bf16 value_h  (A fp32)
  gemm_mfma<2, 1, 256><<<MVP / 128, 512, 0, stream>>>(
      inflat, Btv, b_val, nullptr, vh, nullptr, MV);
  // 2+3 fused: [logits | offsets] = query @ [W_attn | W_off]  (A fp32)
  gemm_mfma<3, 1, 384><<<NQ / 128, 512, 0, stream>>>(
      query, Btc, b_attn, b_off, logits, offb, NQ);
  // 4. sampling (softmax fused, 2 queries/block) -> mid bf16
  msda_sample6<<<NQ / 2, 256, 0, stream>>>(refp, logits, offb, vh, mid);
  // 5. out = mid @ W_out + b_out -> fp32 d_out  (A bf16, lds-dma)
  gemm_mfma<0, 0, 256><<<NQ / 128, 512, 0, stream>>>(
      mid, Btw, b_out, nullptr, out, nullptr, NQ);
}